// Round 1
// baseline (1762.978 us; speedup 1.0000x reference)
//
#include <hip/hip_runtime.h>
#include <hip/hip_bf16.h>

// Problem constants (fixed by the reference).
// B=16384 W=5 L=20 E=50 V=100000 C=128 H=4096 O=50
// h0 row stride padded 250->256; FC1/FC2 processed in 4 chunks of 4096 rows.

// ---------------------------------------------------------------------------
// Kernel W1T: w1t[k][j] = fc1_w[j][k] for k<250 else 0.  [256][4096] fp32
// ---------------------------------------------------------------------------
__global__ void w1t_kernel(const float* __restrict__ fc1_w,
                           float* __restrict__ w1t) {
    int idx = blockIdx.x * 256 + threadIdx.x;   // = k*4096 + j
    int k = idx >> 12;
    int j = idx & 4095;
    w1t[idx] = (k < 250) ? fc1_w[j * 250 + k] : 0.f;
}

// ---------------------------------------------------------------------------
// Kernel A: per word occurrence (wave): gather char emb -> conv1d(k=3,pad=1)
// -> maxpool over L -> + conv_b + word_emb -> h0[b][w*50+o], pad cols 250..255=0
// ---------------------------------------------------------------------------
__global__ __launch_bounds__(256) void conv_kernel(
    const int* __restrict__ x, const int* __restrict__ wci,
    const float* __restrict__ word_emb, const float* __restrict__ char_emb,
    const float* __restrict__ conv_w, const float* __restrict__ conv_b,
    float* __restrict__ h0)
{
    __shared__ float w4[2500 * 4];      // [i(in)][o(out)][k0,k1,k2,pad]
    __shared__ float ceT[4][50 * 24];   // per wave: [i][m], m=0..21 used (pad rows)

    const int tid  = threadIdx.x;
    const int lane = tid & 63;
    const int wv   = tid >> 6;

    // stage conv weights once per block: w4[(i*50+o)*4 + k] = conv_w[o][i][k]
    for (int t = 0; t < 10; ++t) {
        int p = t * 256 + tid;
        if (p < 2500) {
            int i = p / 50, o = p % 50;
            const float* src = conv_w + (o * 50 + i) * 3;
            float4 v; v.x = src[0]; v.y = src[1]; v.z = src[2]; v.w = 0.f;
            *(float4*)&w4[p * 4] = v;
        }
    }
    __syncthreads();

    const int waveg = blockIdx.x * 4 + wv;
    float* ct = ceT[wv];

    for (int wi = 0; wi < 8; ++wi) {
        const int word = waveg * 8 + wi;        // 0..81919
        const int b = word / 5, w = word % 5;
        const int xid = x[word];                 // wave-uniform

        // gather transposed char embeddings into LDS: ct[i*24+m]
        // m=0 and m>=21 are zero padding (l = m-1)
        for (int t = 0; t < 19; ++t) {
            int idx = t * 64 + lane;
            if (idx < 1200) {
                int i = idx / 24, m = idx % 24;
                float v = 0.f;
                if (m >= 1 && m <= 20) {
                    int cid = wci[xid * 20 + (m - 1)];
                    v = char_emb[cid * 50 + i];
                }
                ct[i * 24 + m] = v;
            }
        }
        __syncthreads();

        const int o = (lane < 50) ? lane : 0;
        float acc[20];
        #pragma unroll
        for (int l = 0; l < 20; ++l) acc[l] = 0.f;

        for (int i = 0; i < 50; ++i) {
            float4 wk = *(const float4*)&w4[(i * 50 + o) * 4];
            float cem[24];
            #pragma unroll
            for (int q = 0; q < 6; ++q) {
                float4 cv = *(const float4*)&ct[i * 24 + q * 4];
                cem[q * 4 + 0] = cv.x; cem[q * 4 + 1] = cv.y;
                cem[q * 4 + 2] = cv.z; cem[q * 4 + 3] = cv.w;
            }
            #pragma unroll
            for (int l = 0; l < 20; ++l)
                acc[l] += cem[l] * wk.x + cem[l + 1] * wk.y + cem[l + 2] * wk.z;
        }

        float mx = acc[0];
        #pragma unroll
        for (int l = 1; l < 20; ++l) mx = fmaxf(mx, acc[l]);

        if (lane < 50) {
            float val = mx + conv_b[o] + word_emb[xid * 50 + o];
            h0[b * 256 + w * 50 + o] = val;
        } else if (w == 4 && lane < 56) {
            h0[b * 256 + 250 + (lane - 50)] = 0.f;   // zero K-pad cols
        }
        __syncthreads();
    }
}

// ---------------------------------------------------------------------------
// Kernel B: FC1 fp32 tiled GEMM, 128x128 tile, 8x8 microtile, K=256 (padded).
// h[row][col] = tanh(h0 . fc1_w^T + fc1_b), stored bf16 (chunk-local rows)
// ---------------------------------------------------------------------------
__global__ __launch_bounds__(256) void fc1_kernel(
    const float* __restrict__ h0, const float* __restrict__ w1t,
    const float* __restrict__ fc1_b, __hip_bfloat16* __restrict__ h,
    int rowBase)
{
    __shared__ float As[16][132];   // [k][m]
    __shared__ float Bs[16][128];   // [k][j]
    const int tid = threadIdx.x;
    const int tx = tid & 15, ty = tid >> 4;
    const int m0 = blockIdx.x * 128;
    const int n0 = blockIdx.y * 128;

    float c[8][8] = {};

    for (int kt = 0; kt < 16; ++kt) {
        const int k0 = kt * 16;
        #pragma unroll
        for (int s = 0; s < 2; ++s) {
            int f = s * 256 + tid;
            int m = f >> 2, kq = f & 3;
            float4 av = *(const float4*)&h0[(rowBase + m0 + m) * 256 + k0 + kq * 4];
            As[kq * 4 + 0][m] = av.x; As[kq * 4 + 1][m] = av.y;
            As[kq * 4 + 2][m] = av.z; As[kq * 4 + 3][m] = av.w;
        }
        #pragma unroll
        for (int s = 0; s < 2; ++s) {
            int f = s * 256 + tid;
            int kk = f >> 5, jq = f & 31;
            *(float4*)&Bs[kk][jq * 4] =
                *(const float4*)&w1t[(k0 + kk) * 4096 + n0 + jq * 4];
        }
        __syncthreads();
        #pragma unroll
        for (int kk = 0; kk < 16; ++kk) {
            float a[8], bb[8];
            *(float4*)&a[0]  = *(const float4*)&As[kk][ty * 8];
            *(float4*)&a[4]  = *(const float4*)&As[kk][ty * 8 + 4];
            *(float4*)&bb[0] = *(const float4*)&Bs[kk][tx * 8];
            *(float4*)&bb[4] = *(const float4*)&Bs[kk][tx * 8 + 4];
            #pragma unroll
            for (int i = 0; i < 8; ++i)
                #pragma unroll
                for (int j = 0; j < 8; ++j)
                    c[i][j] += a[i] * bb[j];
        }
        __syncthreads();
    }

    #pragma unroll
    for (int i = 0; i < 8; ++i) {
        int row = m0 + ty * 8 + i;           // chunk-local
        #pragma unroll
        for (int j = 0; j < 8; ++j) {
            int col = n0 + tx * 8 + j;
            float v = c[i][j] + fc1_b[col];
            // tanh(v) = 1 - 2/(exp(2v)+1)  (safe at +/-inf)
            float t = 1.f - 2.f / (__expf(2.f * v) + 1.f);
            h[row * 4096 + col] = __float2bfloat16(t);
        }
    }
}

// ---------------------------------------------------------------------------
// Kernel C: FC2 + softmax. lane = class o (50 of 64), 4 rows/wave, 16 rows/block.
// ---------------------------------------------------------------------------
__global__ __launch_bounds__(256) void fc2_kernel(
    const __hip_bfloat16* __restrict__ h, const float* __restrict__ fc2_w,
    const float* __restrict__ fc2_b, float* __restrict__ out, int rowBase)
{
    __shared__ float ws2[128][52];   // [kk][o]
    __shared__ float hs[16][128];    // [r][kk]
    const int tid = threadIdx.x;
    const int lane = tid & 63, wv = tid >> 6;
    const int rb = blockIdx.x * 16;          // chunk-local row base
    const int o = (lane < 50) ? lane : 0;

    float acc[4] = {0.f, 0.f, 0.f, 0.f};

    for (int kt = 0; kt < 32; ++kt) {
        const int k0 = kt * 128;
        for (int t = 0; t < 25; ++t) {       // 25*256 == 50*128
            int idx = t * 256 + tid;
            int oo = idx >> 7, kk = idx & 127;
            ws2[kk][oo] = fc2_w[oo * 4096 + k0 + kk];
        }
        #pragma unroll
        for (int t = 0; t < 8; ++t) {        // 8*256 == 16*128
            int idx = t * 256 + tid;
            int r = idx >> 7, kk = idx & 127;
            hs[r][kk] = __bfloat162float(h[(rb + r) * 4096 + k0 + kk]);
        }
        __syncthreads();
        #pragma unroll 8
        for (int kk = 0; kk < 128; kk += 4) {
            float w0 = ws2[kk + 0][o], w1 = ws2[kk + 1][o];
            float w2 = ws2[kk + 2][o], w3 = ws2[kk + 3][o];
            #pragma unroll
            for (int r = 0; r < 4; ++r) {
                float4 hv = *(const float4*)&hs[wv * 4 + r][kk];
                acc[r] += hv.x * w0 + hv.y * w1 + hv.z * w2 + hv.w * w3;
            }
        }
        __syncthreads();
    }

    const float bo = (lane < 50) ? fc2_b[o] : 0.f;
    #pragma unroll
    for (int r = 0; r < 4; ++r) {
        float logit = (lane < 50) ? (acc[r] + bo) : -INFINITY;
        float mx = logit;
        for (int off = 32; off > 0; off >>= 1)
            mx = fmaxf(mx, __shfl_xor(mx, off));
        float e = __expf(logit - mx);
        float s = e;
        for (int off = 32; off > 0; off >>= 1)
            s += __shfl_xor(s, off);
        if (lane < 50) {
            int row = rowBase + rb + wv * 4 + r;
            out[row * 50 + lane] = e / s;
        }
    }
}

// ---------------------------------------------------------------------------
extern "C" void kernel_launch(void* const* d_in, const int* in_sizes, int n_in,
                              void* d_out, int out_size, void* d_ws, size_t ws_size,
                              hipStream_t stream) {
    const int*   x        = (const int*)  d_in[0];
    const int*   wci      = (const int*)  d_in[1];
    const float* word_emb = (const float*)d_in[2];
    const float* char_emb = (const float*)d_in[3];
    const float* conv_w   = (const float*)d_in[4];
    const float* conv_b   = (const float*)d_in[5];
    const float* fc1_w    = (const float*)d_in[6];
    const float* fc1_b    = (const float*)d_in[7];
    const float* fc2_w    = (const float*)d_in[8];
    const float* fc2_b    = (const float*)d_in[9];
    float* out = (float*)d_out;

    char* ws = (char*)d_ws;
    float* h0  = (float*)ws;                                   // 16384*256*4  = 16 MB
    float* w1t = (float*)(ws + (size_t)16384 * 256 * 4);       // 256*4096*4   =  4 MB
    __hip_bfloat16* h = (__hip_bfloat16*)(ws + (size_t)16384 * 256 * 4
                                             + (size_t)256 * 4096 * 4);  // 4096*4096*2 = 32 MB

    w1t_kernel<<<4096, 256, 0, stream>>>(fc1_w, w1t);
    conv_kernel<<<2560, 256, 0, stream>>>(x, wci, word_emb, char_emb,
                                          conv_w, conv_b, h0);
    for (int c = 0; c < 4; ++c) {
        int rowBase = c * 4096;
        fc1_kernel<<<dim3(32, 32), 256, 0, stream>>>(h0, w1t, fc1_b, h, rowBase);
        fc2_kernel<<<256, 256, 0, stream>>>(h, fc2_w, fc2_b, out, rowBase);
    }
}

// Round 2
// 1071.372 us; speedup vs baseline: 1.6455x; 1.6455x over previous
//
#include <hip/hip_runtime.h>
#include <hip/hip_bf16.h>

// B=16384 W=5 L=20 E=50 V=100000 C=128 H=4096 O=50
// ha = bf16 [16384][256] (K-padded 250->256), wb = bf16 [4096][256] (fc1_w, [N][K]),
// w2b = bf16 [64][4096] (fc2_w padded to 64 rows), h = bf16 [4096][4096] per chunk.

typedef __attribute__((ext_vector_type(8))) short short8;
typedef __attribute__((ext_vector_type(4))) float float4v;

// ---------------------------------------------------------------------------
// wb[n][k] = bf16(fc1_w[n][k]), k<250 else 0.   [4096][256]
// ---------------------------------------------------------------------------
__global__ void wb_kernel(const float* __restrict__ fc1_w,
                          __hip_bfloat16* __restrict__ wb) {
    int idx = blockIdx.x * 256 + threadIdx.x;     // n*256 + k
    int n = idx >> 8, k = idx & 255;
    wb[idx] = __float2bfloat16(k < 250 ? fc1_w[n * 250 + k] : 0.f);
}

// ---------------------------------------------------------------------------
// w2b[n][k] = bf16(fc2_w[n][k]), n<50 else 0.   [64][4096]
// ---------------------------------------------------------------------------
__global__ void w2b_kernel(const float* __restrict__ fc2_w,
                           __hip_bfloat16* __restrict__ w2b) {
    int idx = blockIdx.x * 256 + threadIdx.x;     // n*4096 + k
    int n = idx >> 12;
    w2b[idx] = __float2bfloat16(n < 50 ? fc2_w[idx] : 0.f);
}

// ---------------------------------------------------------------------------
// conv: per wave per word: char ids -> SGPR (readfirstlane), char_emb reads
// become scalar loads; weights in conflict-free LDS [k][i*50+o]; no LDS for
// ce, no barriers in the word loop. Output bf16 ha[b][w*50+o], cols 250..255=0.
// ---------------------------------------------------------------------------
__global__ __launch_bounds__(256) void conv_kernel(
    const int* __restrict__ x, const int* __restrict__ wci,
    const float* __restrict__ word_emb, const float* __restrict__ char_emb,
    const float* __restrict__ conv_w, const float* __restrict__ conv_b,
    __hip_bfloat16* __restrict__ ha)
{
    __shared__ float wl[3][2500];    // 30 KB, lane-stride-1 in o -> conflict-free
    const int tid  = threadIdx.x;
    const int lane = tid & 63;
    const int wv   = tid >> 6;

    for (int p = tid; p < 7500; p += 256) {
        int k = p / 2500, r = p % 2500;
        int i = r / 50, o = r % 50;
        wl[k][r] = conv_w[(o * 50 + i) * 3 + k];
    }
    __syncthreads();

    const int o = (lane < 50) ? lane : 49;
    const float cb = conv_b[o];

    for (int wi = 0; wi < 8; ++wi) {
        const int word = (blockIdx.x * 4 + wv) * 8 + wi;   // 0..81919
        const int b = word / 5;
        const int w = word - b * 5;
        const int xid = __builtin_amdgcn_readfirstlane(x[word]);
        const int* crow = wci + xid * 20;
        int cid[20];
        #pragma unroll
        for (int m = 0; m < 20; ++m)
            cid[m] = __builtin_amdgcn_readfirstlane(crow[m]) * 50;

        float acc[20];
        #pragma unroll
        for (int l = 0; l < 20; ++l) acc[l] = 0.f;

        #pragma unroll 2
        for (int i = 0; i < 50; ++i) {
            const float w0 = wl[0][i * 50 + o];
            const float w1 = wl[1][i * 50 + o];
            const float w2 = wl[2][i * 50 + o];
            float cf[20];
            #pragma unroll
            for (int m = 0; m < 20; ++m) cf[m] = char_emb[cid[m] + i];  // scalar
            acc[0] += cf[0] * w1 + cf[1] * w2;
            #pragma unroll
            for (int l = 1; l < 19; ++l)
                acc[l] += cf[l - 1] * w0 + cf[l] * w1 + cf[l + 1] * w2;
            acc[19] += cf[18] * w0 + cf[19] * w1;
        }

        float mx = acc[0];
        #pragma unroll
        for (int l = 1; l < 20; ++l) mx = fmaxf(mx, acc[l]);

        if (lane < 50) {
            float val = mx + cb + word_emb[xid * 50 + lane];
            ha[b * 256 + w * 50 + lane] = __float2bfloat16(val);
        } else if (w == 4 && lane < 56) {
            ha[b * 256 + 200 + lane] = __float2bfloat16(0.f);  // cols 250..255
        }
    }
}

// ---------------------------------------------------------------------------
// FC1 bf16 MFMA: 128x128 tile, 4 waves 2x2, each wave 64x64 = 4x4 MFMAs of
// 16x16x32. LDS staged in fragment-linear layout (lane*16B -> conflict-free).
// Epilogue: +bias, tanh, store bf16 h (chunk-local rows).
// ---------------------------------------------------------------------------
__global__ __launch_bounds__(256) void fc1_kernel(
    const __hip_bfloat16* __restrict__ ha, const __hip_bfloat16* __restrict__ wb,
    const float* __restrict__ fc1_b, __hip_bfloat16* __restrict__ h, int rowBase)
{
    __shared__ short8 As[512];   // 8 m-tiles x 64 lanes x 16B = 8 KB
    __shared__ short8 Bs[512];
    const int tid  = threadIdx.x;
    const int lane = tid & 63;
    const int wv   = tid >> 6;
    const int wm = wv >> 1, wn = wv & 1;
    const int m0 = blockIdx.x * 128;
    const int n0 = blockIdx.y * 128;

    float4v acc[4][4] = {};

    for (int kt = 0; kt < 8; ++kt) {
        const int k0 = kt * 32;
        #pragma unroll
        for (int s = 0; s < 2; ++s) {
            int seg = s * 256 + tid;          // 0..511
            int mt = seg >> 6, l = seg & 63;
            int q = l >> 4, m = l & 15;
            As[seg] = *(const short8*)(ha + (size_t)(rowBase + m0 + mt * 16 + m) * 256 + k0 + q * 8);
            Bs[seg] = *(const short8*)(wb + (size_t)(n0 + mt * 16 + m) * 256 + k0 + q * 8);
        }
        __syncthreads();
        short8 av[4], bv[4];
        #pragma unroll
        for (int t = 0; t < 4; ++t) {
            av[t] = As[(wm * 4 + t) * 64 + lane];
            bv[t] = Bs[(wn * 4 + t) * 64 + lane];
        }
        #pragma unroll
        for (int mt = 0; mt < 4; ++mt)
            #pragma unroll
            for (int nt = 0; nt < 4; ++nt)
                acc[mt][nt] = __builtin_amdgcn_mfma_f32_16x16x32_bf16(
                    av[mt], bv[nt], acc[mt][nt], 0, 0, 0);
        __syncthreads();
    }

    const int q = lane >> 4, m = lane & 15;
    #pragma unroll
    for (int mt = 0; mt < 4; ++mt) {
        #pragma unroll
        for (int nt = 0; nt < 4; ++nt) {
            const int col = n0 + wn * 64 + nt * 16 + m;
            const float bias = fc1_b[col];
            #pragma unroll
            for (int r = 0; r < 4; ++r) {
                const int row = m0 + wm * 64 + mt * 16 + q * 4 + r;  // chunk-local
                float v = acc[mt][nt][r] + bias;
                float t = 1.f - 2.f / (__expf(2.f * v) + 1.f);       // tanh
                h[(size_t)row * 4096 + col] = __float2bfloat16(t);
            }
        }
    }
}

// ---------------------------------------------------------------------------
// FC2 bf16 MFMA + fused softmax. Block = 32 rows x 64 cols (N padded), 4 waves
// split K (1024 each), direct global fragment loads, LDS tree-reduce, softmax.
// ---------------------------------------------------------------------------
__global__ __launch_bounds__(256) void fc2_kernel(
    const __hip_bfloat16* __restrict__ h, const __hip_bfloat16* __restrict__ w2b,
    const float* __restrict__ fc2_b, float* __restrict__ out, int rowBase)
{
    __shared__ float part[4][32][64];   // 32 KB
    const int tid  = threadIdx.x;
    const int lane = tid & 63;
    const int wv   = tid >> 6;
    const int rb = blockIdx.x * 32;     // chunk-local row base
    const int m = lane & 15, q = lane >> 4;

    float4v acc[2][4] = {};
    const int kbase = wv * 1024;

    for (int s = 0; s < 32; ++s) {
        const int kk = kbase + s * 32 + q * 8;
        short8 av[2], bv[4];
        #pragma unroll
        for (int mt = 0; mt < 2; ++mt)
            av[mt] = *(const short8*)(h + (size_t)(rb + mt * 16 + m) * 4096 + kk);
        #pragma unroll
        for (int nt = 0; nt < 4; ++nt)
            bv[nt] = *(const short8*)(w2b + (size_t)(nt * 16 + m) * 4096 + kk);
        #pragma unroll
        for (int mt = 0; mt < 2; ++mt)
            #pragma unroll
            for (int nt = 0; nt < 4; ++nt)
                acc[mt][nt] = __builtin_amdgcn_mfma_f32_16x16x32_bf16(
                    av[mt], bv[nt], acc[mt][nt], 0, 0, 0);
    }

    #pragma unroll
    for (int mt = 0; mt < 2; ++mt)
        #pragma unroll
        for (int nt = 0; nt < 4; ++nt)
            #pragma unroll
            for (int r = 0; r < 4; ++r)
                part[wv][mt * 16 + q * 4 + r][nt * 16 + m] = acc[mt][nt][r];
    __syncthreads();

    #pragma unroll
    for (int t = 0; t < 8; ++t) {
        int idx = t * 256 + tid;            // rows partitioned by t: no race
        int row = idx >> 6, col = idx & 63;
        float lg = part[0][row][col] + part[1][row][col]
                 + part[2][row][col] + part[3][row][col];
        part[0][row][col] = (col < 50) ? lg + fc2_b[col] : -1e30f;
    }
    __syncthreads();

    #pragma unroll
    for (int rr = 0; rr < 8; ++rr) {
        const int row = wv * 8 + rr;
        float v = part[0][row][lane];
        float mx = v;
        for (int off = 32; off > 0; off >>= 1) mx = fmaxf(mx, __shfl_xor(mx, off));
        float e = __expf(v - mx);
        float ssum = e;
        for (int off = 32; off > 0; off >>= 1) ssum += __shfl_xor(ssum, off);
        if (lane < 50)
            out[(size_t)(rowBase + rb + row) * 50 + lane] = e / ssum;
    }
}

// ---------------------------------------------------------------------------
extern "C" void kernel_launch(void* const* d_in, const int* in_sizes, int n_in,
                              void* d_out, int out_size, void* d_ws, size_t ws_size,
                              hipStream_t stream) {
    const int*   x        = (const int*)  d_in[0];
    const int*   wci      = (const int*)  d_in[1];
    const float* word_emb = (const float*)d_in[2];
    const float* char_emb = (const float*)d_in[3];
    const float* conv_w   = (const float*)d_in[4];
    const float* conv_b   = (const float*)d_in[5];
    const float* fc1_w    = (const float*)d_in[6];
    const float* fc1_b    = (const float*)d_in[7];
    const float* fc2_w    = (const float*)d_in[8];
    const float* fc2_b    = (const float*)d_in[9];
    float* out = (float*)d_out;

    char* ws = (char*)d_ws;
    __hip_bfloat16* ha  = (__hip_bfloat16*)ws;                               // 8 MB
    __hip_bfloat16* wb  = (__hip_bfloat16*)(ws + ((size_t)8 << 20));         // 2 MB
    __hip_bfloat16* w2b = (__hip_bfloat16*)(ws + ((size_t)10 << 20));        // 0.5 MB
    __hip_bfloat16* h   = (__hip_bfloat16*)(ws + ((size_t)10 << 20) + ((size_t)512 << 10)); // 32 MB

    wb_kernel<<<4096, 256, 0, stream>>>(fc1_w, wb);
    w2b_kernel<<<1024, 256, 0, stream>>>(fc2_w, w2b);
    conv_kernel<<<2560, 256, 0, stream>>>(x, wci, word_emb, char_emb,
                                          conv_w, conv_b, ha);
    for (int c = 0; c < 4; ++c) {
        const int rowBase = c * 4096;
        fc1_kernel<<<dim3(32, 32), 256, 0, stream>>>(ha, wb, fc1_b, h, rowBase);
        fc2_kernel<<<128, 256, 0, stream>>>(h, w2b, fc2_b, out, rowBase);
    }
}

// Round 3
// 508.787 us; speedup vs baseline: 3.4651x; 2.1057x over previous
//
#include <hip/hip_runtime.h>
#include <hip/hip_bf16.h>

// B=16384 W=5 L=20 E=50 V=100000 C=128 H=4096 O=50
// ha  = bf16 [16384][256] (K-padded 250->256)
// wb  = bf16 [4096][256]  (fc1_w as [N][K])
// w2b = bf16 [64][4096]   (fc2_w padded to 64 rows)
// h   = bf16 [4096][4096] per chunk
// wbc = conv weights pre-packed in MFMA B-fragment order, [12 ntile][2 kstep][64 lane] short8

typedef __attribute__((ext_vector_type(8))) short short8;
typedef __attribute__((ext_vector_type(4))) float float4v;

__device__ inline short bf16b(float f) {
    __hip_bfloat16 h = __float2bfloat16(f);
    return *reinterpret_cast<short*>(&h);
}

// ---------------------------------------------------------------------------
__global__ void wb_kernel(const float* __restrict__ fc1_w,
                          __hip_bfloat16* __restrict__ wb) {
    int idx = blockIdx.x * 256 + threadIdx.x;     // n*256 + k
    int n = idx >> 8, k = idx & 255;
    wb[idx] = __float2bfloat16(k < 250 ? fc1_w[n * 250 + k] : 0.f);
}

// ---------------------------------------------------------------------------
__global__ void w2b_kernel(const float* __restrict__ fc2_w,
                           __hip_bfloat16* __restrict__ w2b) {
    int idx = blockIdx.x * 256 + threadIdx.x;     // n*4096 + k
    int n = idx >> 12;
    w2b[idx] = __float2bfloat16(n < 50 ? fc2_w[idx] : 0.f);
}

// ---------------------------------------------------------------------------
// conv weights -> B-fragment order. GEMM is G[r][n] = sum_i ce[r][i]*Wmat[i][n],
// n = kk*64 + o, Wmat[i][n] = conv_w[(o*50+i)*3+kk] (zero for o>=50 or i>=50).
// B-frag (as [N][K] row-major): frag[t2*64+lane][j] = Wmat[i = s*32+(lane>>4)*8+j][n = nt*16+(lane&15)]
// ---------------------------------------------------------------------------
__global__ void wbc_kernel(const float* __restrict__ conv_w,
                           short* __restrict__ wbc) {
    int idx = blockIdx.x * 256 + threadIdx.x;     // 0..1535
    if (idx >= 1536) return;
    int t2 = idx >> 6, lane = idx & 63;
    int s = t2 & 1, nt = t2 >> 1;
    int kg = lane >> 4, c = lane & 15;
    int n = nt * 16 + c, kk = n >> 6, o = n & 63;
    short8 v;
    #pragma unroll
    for (int j = 0; j < 8; ++j) {
        int i = s * 32 + kg * 8 + j;
        float f = (o < 50 && i < 50) ? conv_w[(o * 50 + i) * 3 + kk] : 0.f;
        v[j] = bf16b(f);
    }
    *(short8*)(wbc + (size_t)idx * 8) = v;
}

// ---------------------------------------------------------------------------
// zero ha pad cols 250..255
// ---------------------------------------------------------------------------
__global__ void haPad_kernel(__hip_bfloat16* __restrict__ ha) {
    int idx = blockIdx.x * 256 + threadIdx.x;     // 0..98303 = b*6 + j
    int b = idx / 6, j = idx - b * 6;
    ha[b * 256 + 250 + j] = __float2bfloat16(0.f);
}

// ---------------------------------------------------------------------------
// conv via MFMA. Block = 4 words = 80 rows (5 m-tiles), K=64 (E pad), N=192.
// Wave wv owns n-tiles wv*3..wv*3+2. G written to LDS fp32 (stride 196),
// epilogue: shift-add the 3 taps, maxpool over l, + conv_b + word_emb -> ha.
// ---------------------------------------------------------------------------
__global__ __launch_bounds__(256) void conv_kernel(
    const int* __restrict__ x, const int* __restrict__ wci,
    const float* __restrict__ word_emb, const float* __restrict__ char_emb,
    const float* __restrict__ conv_b, const short* __restrict__ wbc,
    __hip_bfloat16* __restrict__ ha)
{
    __shared__ short8 As[640];          // 5 mtile x 2 kstep x 64 lanes, 10 KB
    __shared__ float  Gs[80 * 196];     // 62.7 KB, stride 196 (2-way max aliasing)

    const int tid  = threadIdx.x;
    const int lane = tid & 63;
    const int wv   = tid >> 6;
    const int gw0  = blockIdx.x * 4;

    // ---- stage A: gather char embeddings -> bf16 fragments in LDS ----
    for (int it = tid; it < 640; it += 256) {
        const int r = it >> 3, q = it & 7;       // row 0..79, kchunk 0..7
        const int w = r / 20, mp = r - w * 20;
        const int xid = x[gw0 + w];
        const int cid = wci[xid * 20 + mp];
        const float* src = char_emb + cid * 50;
        float f[8];
        #pragma unroll
        for (int p = 0; p < 4; ++p) {
            const int i = q * 8 + p * 2;
            if (i < 50) {
                float2 t = *(const float2*)(src + i);
                f[2 * p] = t.x; f[2 * p + 1] = t.y;
            } else { f[2 * p] = 0.f; f[2 * p + 1] = 0.f; }
        }
        short8 v;
        #pragma unroll
        for (int j = 0; j < 8; ++j) v[j] = bf16b(f[j]);
        const int mt = r >> 4, m = r & 15, ss = q >> 2, kg = q & 3;
        As[(mt * 2 + ss) * 64 + kg * 16 + m] = v;
    }
    __syncthreads();

    // ---- MFMA: 5 m-tiles x 3 n-tiles x 2 k-steps ----
    float4v acc[5][3] = {};
    #pragma unroll
    for (int s = 0; s < 2; ++s) {
        short8 av[5], bv[3];
        #pragma unroll
        for (int mt = 0; mt < 5; ++mt) av[mt] = As[(mt * 2 + s) * 64 + lane];
        #pragma unroll
        for (int j = 0; j < 3; ++j)
            bv[j] = *(const short8*)(wbc + (size_t)(((wv * 3 + j) * 2 + s) * 64 + lane) * 8);
        #pragma unroll
        for (int mt = 0; mt < 5; ++mt)
            #pragma unroll
            for (int j = 0; j < 3; ++j)
                acc[mt][j] = __builtin_amdgcn_mfma_f32_16x16x32_bf16(
                    av[mt], bv[j], acc[mt][j], 0, 0, 0);
    }

    // ---- write G to LDS (C layout: col=lane&15, row=q*4+r) ----
    {
        const int q = lane >> 4, c = lane & 15;
        #pragma unroll
        for (int mt = 0; mt < 5; ++mt)
            #pragma unroll
            for (int j = 0; j < 3; ++j) {
                const int col = (wv * 3 + j) * 16 + c;
                #pragma unroll
                for (int r = 0; r < 4; ++r)
                    Gs[(mt * 16 + q * 4 + r) * 196 + col] = acc[mt][j][r];
            }
    }
    __syncthreads();

    // ---- epilogue: conv[l] = G0[l-1] + G1[l] + G2[l+1], maxpool, bias+emb ----
    if (tid < 200) {
        const int w = tid / 50, o = tid - w * 50;
        const int gw = gw0 + w;
        const float* g = Gs + w * 20 * 196;
        float mx = -1e30f;
        #pragma unroll
        for (int l = 0; l < 20; ++l) {
            float v = g[l * 196 + 64 + o];                       // G1[l]
            if (l > 0)  v += g[(l - 1) * 196 + o];               // G0[l-1]
            if (l < 19) v += g[(l + 1) * 196 + 128 + o];         // G2[l+1]
            mx = fmaxf(mx, v);
        }
        const int xid = x[gw];
        const float val = mx + conv_b[o] + word_emb[xid * 50 + o];
        const int b = gw / 5, wp = gw - b * 5;
        ha[b * 256 + wp * 50 + o] = __float2bfloat16(val);
    }
}

// ---------------------------------------------------------------------------
// FC1 bf16 MFMA (unchanged from R2): 128x128 tile, 4 waves 2x2.
// ---------------------------------------------------------------------------
__global__ __launch_bounds__(256) void fc1_kernel(
    const __hip_bfloat16* __restrict__ ha, const __hip_bfloat16* __restrict__ wb,
    const float* __restrict__ fc1_b, __hip_bfloat16* __restrict__ h, int rowBase)
{
    __shared__ short8 As[512];
    __shared__ short8 Bs[512];
    const int tid  = threadIdx.x;
    const int lane = tid & 63;
    const int wv   = tid >> 6;
    const int wm = wv >> 1, wn = wv & 1;
    const int m0 = blockIdx.x * 128;
    const int n0 = blockIdx.y * 128;

    float4v acc[4][4] = {};

    for (int kt = 0; kt < 8; ++kt) {
        const int k0 = kt * 32;
        #pragma unroll
        for (int s = 0; s < 2; ++s) {
            int seg = s * 256 + tid;
            int mt = seg >> 6, l = seg & 63;
            int q = l >> 4, m = l & 15;
            As[seg] = *(const short8*)(ha + (size_t)(rowBase + m0 + mt * 16 + m) * 256 + k0 + q * 8);
            Bs[seg] = *(const short8*)(wb + (size_t)(n0 + mt * 16 + m) * 256 + k0 + q * 8);
        }
        __syncthreads();
        short8 av[4], bv[4];
        #pragma unroll
        for (int t = 0; t < 4; ++t) {
            av[t] = As[(wm * 4 + t) * 64 + lane];
            bv[t] = Bs[(wn * 4 + t) * 64 + lane];
        }
        #pragma unroll
        for (int mt = 0; mt < 4; ++mt)
            #pragma unroll
            for (int nt = 0; nt < 4; ++nt)
                acc[mt][nt] = __builtin_amdgcn_mfma_f32_16x16x32_bf16(
                    av[mt], bv[nt], acc[mt][nt], 0, 0, 0);
        __syncthreads();
    }

    const int q = lane >> 4, m = lane & 15;
    #pragma unroll
    for (int mt = 0; mt < 4; ++mt) {
        #pragma unroll
        for (int nt = 0; nt < 4; ++nt) {
            const int col = n0 + wn * 64 + nt * 16 + m;
            const float bias = fc1_b[col];
            #pragma unroll
            for (int r = 0; r < 4; ++r) {
                const int row = m0 + wm * 64 + mt * 16 + q * 4 + r;
                float v = acc[mt][nt][r] + bias;
                float t = 1.f - 2.f / (__expf(2.f * v) + 1.f);
                h[(size_t)row * 4096 + col] = __float2bfloat16(t);
            }
        }
    }
}

// ---------------------------------------------------------------------------
// FC2 bf16 MFMA + fused softmax (unchanged from R2).
// ---------------------------------------------------------------------------
__global__ __launch_bounds__(256) void fc2_kernel(
    const __hip_bfloat16* __restrict__ h, const __hip_bfloat16* __restrict__ w2b,
    const float* __restrict__ fc2_b, float* __restrict__ out, int rowBase)
{
    __shared__ float part[4][32][64];
    const int tid  = threadIdx.x;
    const int lane = tid & 63;
    const int wv   = tid >> 6;
    const int rb = blockIdx.x * 32;
    const int m = lane & 15, q = lane >> 4;

    float4v acc[2][4] = {};
    const int kbase = wv * 1024;

    for (int s = 0; s < 32; ++s) {
        const int kk = kbase + s * 32 + q * 8;
        short8 av[2], bv[4];
        #pragma unroll
        for (int mt = 0; mt < 2; ++mt)
            av[mt] = *(const short8*)(h + (size_t)(rb + mt * 16 + m) * 4096 + kk);
        #pragma unroll
        for (int nt = 0; nt < 4; ++nt)
            bv[nt] = *(const short8*)(w2b + (size_t)(nt * 16 + m) * 4096 + kk);
        #pragma unroll
        for (int mt = 0; mt < 2; ++mt)
            #pragma unroll
            for (int nt = 0; nt < 4; ++nt)
                acc[mt][nt] = __builtin_amdgcn_mfma_f32_16x16x32_bf16(
                    av[mt], bv[nt], acc[mt][nt], 0, 0, 0);
    }

    #pragma unroll
    for (int mt = 0; mt < 2; ++mt)
        #pragma unroll
        for (int nt = 0; nt < 4; ++nt)
            #pragma unroll
            for (int r = 0; r < 4; ++r)
                part[wv][mt * 16 + q * 4 + r][nt * 16 + m] = acc[mt][nt][r];
    __syncthreads();

    #pragma unroll
    for (int t = 0; t < 8; ++t) {
        int idx = t * 256 + tid;
        int row = idx >> 6, col = idx & 63;
        float lg = part[0][row][col] + part[1][row][col]
                 + part[2][row][col] + part[3][row][col];
        part[0][row][col] = (col < 50) ? lg + fc2_b[col] : -1e30f;
    }
    __syncthreads();

    #pragma unroll
    for (int rr = 0; rr < 8; ++rr) {
        const int row = wv * 8 + rr;
        float v = part[0][row][lane];
        float mx = v;
        for (int off = 32; off > 0; off >>= 1) mx = fmaxf(mx, __shfl_xor(mx, off));
        float e = __expf(v - mx);
        float ssum = e;
        for (int off = 32; off > 0; off >>= 1) ssum += __shfl_xor(ssum, off);
        if (lane < 50)
            out[(size_t)(rowBase + rb + row) * 50 + lane] = e / ssum;
    }
}

// ---------------------------------------------------------------------------
extern "C" void kernel_launch(void* const* d_in, const int* in_sizes, int n_in,
                              void* d_out, int out_size, void* d_ws, size_t ws_size,
                              hipStream_t stream) {
    const int*   x        = (const int*)  d_in[0];
    const int*   wci      = (const int*)  d_in[1];
    const float* word_emb = (const float*)d_in[2];
    const float* char_emb = (const float*)d_in[3];
    const float* conv_w   = (const float*)d_in[4];
    const float* conv_b   = (const float*)d_in[5];
    const float* fc1_w    = (const float*)d_in[6];
    const float* fc1_b    = (const float*)d_in[7];
    const float* fc2_w    = (const float*)d_in[8];
    const float* fc2_b    = (const float*)d_in[9];
    float* out = (float*)d_out;

    char* ws = (char*)d_ws;
    __hip_bfloat16* ha  = (__hip_bfloat16*)ws;                                  // 8 MB
    __hip_bfloat16* wb  = (__hip_bfloat16*)(ws + ((size_t)8 << 20));            // 2 MB
    __hip_bfloat16* w2b = (__hip_bfloat16*)(ws + ((size_t)10 << 20));           // 0.5 MB
    __hip_bfloat16* h   = (__hip_bfloat16*)(ws + ((size_t)10 << 20) + ((size_t)512 << 10)); // 32 MB
    short*          wbcp = (short*)(ws + ((size_t)42 << 20) + ((size_t)512 << 10));         // 24 KB

    wb_kernel<<<4096, 256, 0, stream>>>(fc1_w, wb);
    w2b_kernel<<<1024, 256, 0, stream>>>(fc2_w, w2b);
    wbc_kernel<<<6, 256, 0, stream>>>(conv_w, wbcp);
    haPad_kernel<<<384, 256, 0, stream>>>(ha);
    conv_kernel<<<20480, 256, 0, stream>>>(x, wci, word_emb, char_emb,
                                           conv_b, wbcp, ha);
    for (int c = 0; c < 4; ++c) {
        const int rowBase = c * 4096;
        fc1_kernel<<<dim3(32, 32), 256, 0, stream>>>(ha, wb, fc1_b, h, rowBase);
        fc2_kernel<<<128, 256, 0, stream>>>(h, w2b, fc2_b, out, rowBase);
    }
}